// Round 1
// baseline (299.701 us; speedup 1.0000x reference)
//
#include <hip/hip_runtime.h>
#include <cstdint>
#include <cstddef>

// ---------------------------------------------------------------------------
// LSTM cell: gates = [x|h] (2048x4096) · [W_ih|W_hh]^T (8192x4096) + b
// Plan: fp32->bf16 pack (ws) -> bf16 MFMA GEMM (m97 structure) -> epilogue
// ---------------------------------------------------------------------------

typedef __attribute__((ext_vector_type(8))) short bf16x8;
typedef __attribute__((ext_vector_type(4))) float f32x4;

#define GLD_AS1 const __attribute__((address_space(1))) void
#define GLD_AS3 __attribute__((address_space(3))) void

__device__ __forceinline__ void gload_lds16(const void* g, void* l) {
  __builtin_amdgcn_global_load_lds((GLD_AS1*)g, (GLD_AS3*)l, 16, 0, 0);
}

__device__ __forceinline__ unsigned short f2bf(float f) {
  unsigned int u = __float_as_uint(f);
  unsigned int r = 0x7FFFu + ((u >> 16) & 1u);
  return (unsigned short)((u + r) >> 16);
}

// ---- pack fp32 (rows x 2048) into bf16 (rows x 4096) at column offset -----
__global__ __launch_bounds__(256) void cvt2048(const float* __restrict__ src,
                                               unsigned short* __restrict__ dst,
                                               int col_off, int total4) {
  int i = blockIdx.x * 256 + threadIdx.x;
  if (i >= total4) return;
  int flat = i << 2;                 // element index in src
  int r = flat >> 11;                // src cols = 2048
  int c = flat & 2047;
  float4 v = *(const float4*)(src + flat);
  ushort4 o;
  o.x = f2bf(v.x); o.y = f2bf(v.y); o.z = f2bf(v.z); o.w = f2bf(v.w);
  *(ushort4*)(dst + (((size_t)r) << 12) + col_off + c) = o;  // dst stride 4096
}

// ---- bf16 GEMM: gates[2048x8192] = A[2048x4096] * W[8192x4096]^T + bias ---
// m97 structure: 128x128 tile, BK=32, 256 threads (4 waves, 2x2), 16x16x32 MFMA
__global__ __launch_bounds__(256) void gemm_gates(
    const unsigned short* __restrict__ A,   // [2048][4096] bf16
    const unsigned short* __restrict__ W,   // [8192][4096] bf16
    const float* __restrict__ b_ih, const float* __restrict__ b_hh,
    float* __restrict__ gates)              // [2048][8192] fp32
{
  constexpr int M = 2048, N = 8192, K = 4096;
  constexpr int BK = 32;
  __shared__ alignas(16) unsigned short As[128 * BK];
  __shared__ alignas(16) unsigned short Bs[128 * BK];

  // XCD-aware swizzle (nwg=1024, divisible by 8 -> bijective)
  constexpr int nbx = N / 128;  // 64
  constexpr int nwg = (M / 128) * nbx;  // 1024
  int lin = blockIdx.x;
  lin = (lin & 7) * (nwg >> 3) + (lin >> 3);
  int bm = (lin / nbx) * 128;
  int bn = (lin % nbx) * 128;

  int tid  = threadIdx.x;
  int lane = tid & 63;
  int w    = tid >> 6;          // wave 0..3
  int wm   = (w >> 1) * 64;
  int wn   = (w & 1) * 64;

  f32x4 acc[4][4] = {};

  // staging geometry: chunk = 1KB (64 lanes x 16B); 8 chunks per 8KB tile
  int srow = (w * 2) * 16 + (lane >> 2);       // chunk base row for it=0
  int scol = (lane & 3) * 8;                   // bf16 col within row

  for (int k0 = 0; k0 < K; k0 += BK) {
#pragma unroll
    for (int it = 0; it < 2; ++it) {
      int chunk = w * 2 + it;
      int row = srow + it * 16;
      const unsigned short* ga = A + (size_t)(bm + row) * K + k0 + scol;
      const unsigned short* gb = W + (size_t)(bn + row) * K + k0 + scol;
      gload_lds16(ga, &As[chunk * 512]);
      gload_lds16(gb, &Bs[chunk * 512]);
    }
    __syncthreads();

    bf16x8 af[4], bfr[4];
#pragma unroll
    for (int mf = 0; mf < 4; ++mf)
      af[mf] = *(const bf16x8*)&As[(wm + mf * 16 + (lane & 15)) * BK + (lane >> 4) * 8];
#pragma unroll
    for (int nf = 0; nf < 4; ++nf)
      bfr[nf] = *(const bf16x8*)&Bs[(wn + nf * 16 + (lane & 15)) * BK + (lane >> 4) * 8];
#pragma unroll
    for (int mf = 0; mf < 4; ++mf)
#pragma unroll
      for (int nf = 0; nf < 4; ++nf)
        acc[mf][nf] = __builtin_amdgcn_mfma_f32_16x16x32_bf16(af[mf], bfr[nf], acc[mf][nf], 0, 0, 0);
    __syncthreads();
  }

  // C-write + fused bias. C/D layout: col=lane&15, row=(lane>>4)*4+j (m89)
#pragma unroll
  for (int nf = 0; nf < 4; ++nf) {
    int col = bn + wn + nf * 16 + (lane & 15);
    float bias = b_ih[col] + b_hh[col];
#pragma unroll
    for (int mf = 0; mf < 4; ++mf) {
      int row0 = bm + wm + mf * 16 + (lane >> 4) * 4;
#pragma unroll
      for (int j = 0; j < 4; ++j)
        gates[(size_t)(row0 + j) * N + col] = acc[mf][nf][j] + bias;
    }
  }
}

// ---- elementwise LSTM epilogue --------------------------------------------
__device__ __forceinline__ float sigm(float x) { return 1.0f / (1.0f + __expf(-x)); }

__global__ __launch_bounds__(256) void lstm_epi(const float* __restrict__ gates,
                                                const float* __restrict__ C_prev,
                                                float* __restrict__ out, int total4) {
  int i = blockIdx.x * 256 + threadIdx.x;
  if (i >= total4) return;
  int flat = i << 2;                 // b*2048 + h
  int b = flat >> 11;
  int h = flat & 2047;
  const float* grow = gates + (((size_t)b) << 13);
  float4 vi = *(const float4*)(grow + h);
  float4 vf = *(const float4*)(grow + 2048 + h);
  float4 vg = *(const float4*)(grow + 4096 + h);
  float4 vo = *(const float4*)(grow + 6144 + h);
  float4 cp = *(const float4*)(C_prev + flat);

  float4 nh, nc, fg, ig, gg, og;
  const float* pi = (const float*)&vi;
  const float* pf = (const float*)&vf;
  const float* pg = (const float*)&vg;
  const float* po = (const float*)&vo;
  const float* pc = (const float*)&cp;
  float* onh = (float*)&nh; float* onc = (float*)&nc;
  float* ofg = (float*)&fg; float* oig = (float*)&ig;
  float* ogg = (float*)&gg; float* oog = (float*)&og;
#pragma unroll
  for (int j = 0; j < 4; ++j) {
    float I = sigm(pi[j]);
    float F = sigm(pf[j]);
    float G = tanhf(pg[j]);
    float O = sigm(po[j]);
    float C = F * pc[j] + I * G;
    float H = O * tanhf(C);
    oig[j] = I; ofg[j] = F; ogg[j] = G; oog[j] = O; onc[j] = C; onh[j] = H;
  }
  constexpr size_t SEC = (size_t)2048 * 2048;
  *(float4*)(out + 0 * SEC + flat) = nh;   // new_h
  *(float4*)(out + 1 * SEC + flat) = nc;   // new_C
  *(float4*)(out + 2 * SEC + flat) = fg;   // forget
  *(float4*)(out + 3 * SEC + flat) = ig;   // input
  *(float4*)(out + 4 * SEC + flat) = gg;   // candidate
  *(float4*)(out + 5 * SEC + flat) = og;   // output gate
}

// ---------------------------------------------------------------------------
extern "C" void kernel_launch(void* const* d_in, const int* in_sizes, int n_in,
                              void* d_out, int out_size, void* d_ws, size_t ws_size,
                              hipStream_t stream) {
  const float* x   = (const float*)d_in[0];
  const float* h   = (const float*)d_in[1];
  const float* Cp  = (const float*)d_in[2];
  const float* Wih = (const float*)d_in[3];
  const float* bih = (const float*)d_in[4];
  const float* Whh = (const float*)d_in[5];
  const float* bhh = (const float*)d_in[6];
  float* out = (float*)d_out;

  uint8_t* ws = (uint8_t*)d_ws;
  unsigned short* Abf  = (unsigned short*)ws;                          // 16 MiB: 2048x4096 bf16
  unsigned short* Wbf  = (unsigned short*)(ws + (size_t)(16u << 20));  // 64 MiB: 8192x4096 bf16
  float*          gates = (float*)(ws + (size_t)(80u << 20));          // 64 MiB: 2048x8192 fp32

  // pack A = [x | h_prev]
  cvt2048<<<4096, 256, 0, stream>>>(x, Abf, 0,    1048576);
  cvt2048<<<4096, 256, 0, stream>>>(h, Abf, 2048, 1048576);
  // pack W = [W_ih | W_hh]
  cvt2048<<<16384, 256, 0, stream>>>(Wih, Wbf, 0,    4194304);
  cvt2048<<<16384, 256, 0, stream>>>(Whh, Wbf, 2048, 4194304);

  // GEMM: 1024 blocks (16 x 64 tiles)
  gemm_gates<<<1024, 256, 0, stream>>>(Abf, Wbf, bih, bhh, gates);

  // epilogue
  lstm_epi<<<4096, 256, 0, stream>>>(gates, Cp, out, 1048576);
}